// Round 1
// baseline (723.144 us; speedup 1.0000x reference)
//
#include <hip/hip_runtime.h>
#include <math.h>

#define IN_F 256
#define NHEAD 8
#define FDIM 32
#define SCAN_B 512

// ---------------- CSR build ----------------

__global__ __launch_bounds__(256) void hist_k(const int* __restrict__ dst,
                                              int* __restrict__ deg, int E) {
  int i = blockIdx.x * 256 + threadIdx.x;
  if (i < E) atomicAdd(&deg[dst[i]], 1);
}

__global__ __launch_bounds__(SCAN_B) void scan1_k(const int* __restrict__ deg,
                                                  int* __restrict__ offs,
                                                  int* __restrict__ bsum, int N) {
  __shared__ int s[SCAN_B];
  int t = threadIdx.x;
  int i = blockIdx.x * SCAN_B + t;
  s[t] = (i < N) ? deg[i] : 0;
  __syncthreads();
  for (int off = 1; off < SCAN_B; off <<= 1) {
    int add = (t >= off) ? s[t - off] : 0;
    __syncthreads();
    s[t] += add;
    __syncthreads();
  }
  if (i < N) offs[i + 1] = s[t];
  if (t == SCAN_B - 1) bsum[blockIdx.x] = s[t];
}

__global__ __launch_bounds__(SCAN_B) void scan2_k(int* __restrict__ bsum, int nb) {
  __shared__ int s[SCAN_B];
  int t = threadIdx.x;
  s[t] = (t < nb) ? bsum[t] : 0;
  __syncthreads();
  for (int off = 1; off < SCAN_B; off <<= 1) {
    int add = (t >= off) ? s[t - off] : 0;
    __syncthreads();
    s[t] += add;
    __syncthreads();
  }
  if (t < nb) bsum[t] = (t == 0) ? 0 : s[t - 1];
}

__global__ __launch_bounds__(SCAN_B) void scan3_k(int* __restrict__ offs,
                                                  const int* __restrict__ bsum, int N) {
  int i = blockIdx.x * SCAN_B + threadIdx.x;
  if (i < N) offs[i + 1] += bsum[blockIdx.x];
  if (i == 0) offs[0] = 0;
}

__global__ __launch_bounds__(256) void scatter_k(const int* __restrict__ src,
                                                 const int* __restrict__ dst,
                                                 const int* __restrict__ offs,
                                                 int* __restrict__ cursor,
                                                 int* __restrict__ esrc, int E) {
  int i = blockIdx.x * 256 + threadIdx.x;
  if (i < E) {
    int d = dst[i];
    int pos = offs[d] + atomicAdd(&cursor[d], 1);
    esrc[pos] = src[i];
  }
}

// ---------------- GEMM1: C(MxN) = A(MxK) @ B(KxN), K,N mult of 16/64 ----------------
// 64x64 tile, 256 threads (16x16), 4x4 per thread, K-tile 16, fp32 vector FMA.
__global__ __launch_bounds__(256) void gemm_xw_k(const float* __restrict__ A,
                                                 const float* __restrict__ B,
                                                 float* __restrict__ C,
                                                 int M, int K, int N) {
  __shared__ float As[16][68];  // [k][row], padded
  __shared__ float Bs[16][64];  // [k][col]
  int t = threadIdx.x;
  int tx = t & 15, ty = t >> 4;
  int row0 = blockIdx.x * 64, col0 = blockIdx.y * 64;
  int lr = t >> 2, lq = t & 3;    // A-tile load: row 0..63, quad 0..3
  int br = t >> 4, bq = t & 15;   // B-tile load: row 0..15, quad 0..15
  float acc[4][4] = {};
  for (int kt = 0; kt < K; kt += 16) {
    float4 va = make_float4(0.f, 0.f, 0.f, 0.f);
    if (row0 + lr < M)
      va = *reinterpret_cast<const float4*>(&A[(size_t)(row0 + lr) * K + kt + lq * 4]);
    float4 vb = *reinterpret_cast<const float4*>(&B[(size_t)(kt + br) * N + col0 + bq * 4]);
    As[lq * 4 + 0][lr] = va.x;
    As[lq * 4 + 1][lr] = va.y;
    As[lq * 4 + 2][lr] = va.z;
    As[lq * 4 + 3][lr] = va.w;
    Bs[br][bq * 4 + 0] = vb.x;
    Bs[br][bq * 4 + 1] = vb.y;
    Bs[br][bq * 4 + 2] = vb.z;
    Bs[br][bq * 4 + 3] = vb.w;
    __syncthreads();
#pragma unroll
    for (int kk = 0; kk < 16; ++kk) {
      float4 a4 = *reinterpret_cast<const float4*>(&As[kk][ty * 4]);
      float4 b4 = *reinterpret_cast<const float4*>(&Bs[kk][tx * 4]);
      float a[4] = {a4.x, a4.y, a4.z, a4.w};
      float b[4] = {b4.x, b4.y, b4.z, b4.w};
#pragma unroll
      for (int i = 0; i < 4; ++i)
#pragma unroll
        for (int j = 0; j < 4; ++j) acc[i][j] = fmaf(a[i], b[j], acc[i][j]);
    }
    __syncthreads();
  }
#pragma unroll
  for (int i = 0; i < 4; ++i) {
    int r = row0 + ty * 4 + i;
    if (r < M)
      *reinterpret_cast<float4*>(&C[(size_t)r * N + col0 + tx * 4]) =
          make_float4(acc[i][0], acc[i][1], acc[i][2], acc[i][3]);
  }
}

// ---------------- GEMM2: Z2(Mx256) = H(Mx32) @ W2(32x256) ----------------
// block: 16 rows, 256 threads (64 col-groups x 4 row-groups), 4x4 per thread.
__global__ __launch_bounds__(256) void gemm_h_k(const float* __restrict__ Hmat,
                                                const float* __restrict__ W2,
                                                float* __restrict__ Z2, int M) {
  __shared__ float Ws[32][256];  // 32 KB
  __shared__ float Hs[32][20];   // [k][row], 16 rows padded
  int t = threadIdx.x;
  for (int i = t; i < 32 * 256; i += 256) Ws[i >> 8][i & 255] = W2[i];
  int row0 = blockIdx.x * 16;
  for (int i = t; i < 16 * 32; i += 256) {
    int r = i >> 5, k = i & 31;
    Hs[k][r] = (row0 + r < M) ? Hmat[(size_t)(row0 + r) * 32 + k] : 0.f;
  }
  __syncthreads();
  int tx = t & 63, ty = t >> 6;
  float acc[4][4] = {};
#pragma unroll
  for (int k = 0; k < 32; ++k) {
    float4 a4 = *reinterpret_cast<const float4*>(&Hs[k][ty * 4]);
    float4 b4 = *reinterpret_cast<const float4*>(&Ws[k][tx * 4]);
    float a[4] = {a4.x, a4.y, a4.z, a4.w};
    float b[4] = {b4.x, b4.y, b4.z, b4.w};
#pragma unroll
    for (int i = 0; i < 4; ++i)
#pragma unroll
      for (int j = 0; j < 4; ++j) acc[i][j] = fmaf(a[i], b[j], acc[i][j]);
  }
#pragma unroll
  for (int i = 0; i < 4; ++i) {
    int r = row0 + ty * 4 + i;
    if (r < M)
      *reinterpret_cast<float4*>(&Z2[(size_t)r * 256 + tx * 4]) =
          make_float4(acc[i][0], acc[i][1], acc[i][2], acc[i][3]);
  }
}

// ---------------- attention logits: el/er[n][h] = sum_f z[n][h][f]*a[h][f] ----------------
// one wave per node; lane l holds float4 l of the 256-float row; head = l/8.
__global__ __launch_bounds__(256) void logits_k(const float* __restrict__ Z,
                                                const float* __restrict__ al,
                                                const float* __restrict__ ar,
                                                float* __restrict__ el,
                                                float* __restrict__ er, int N) {
  int wave = threadIdx.x >> 6;
  int lane = threadIdx.x & 63;
  int n = blockIdx.x * 4 + wave;
  if (n >= N) return;
  float4 z4 = reinterpret_cast<const float4*>(Z)[(size_t)n * 64 + lane];
  float4 a4 = reinterpret_cast<const float4*>(al)[lane];
  float4 r4 = reinterpret_cast<const float4*>(ar)[lane];
  float pl = z4.x * a4.x + z4.y * a4.y + z4.z * a4.z + z4.w * a4.w;
  float pr = z4.x * r4.x + z4.y * r4.y + z4.z * r4.z + z4.w * r4.w;
  pl += __shfl_xor(pl, 1); pl += __shfl_xor(pl, 2); pl += __shfl_xor(pl, 4);
  pr += __shfl_xor(pr, 1); pr += __shfl_xor(pr, 2); pr += __shfl_xor(pr, 4);
  if ((lane & 7) == 0) {
    int h = lane >> 3;
    el[(size_t)n * 8 + h] = pl;
    er[(size_t)n * 8 + h] = pr;
  }
}

// ---------------- per-dst online-softmax aggregation ----------------
// block = 1 dst node, 256 threads; thread -> (head = t/32, feat = t%32).
// LAYER1: epilogue = mean over heads + ELU -> out[n][32]
// else:   epilogue = mean over heads      -> out[n][32]
template <bool LAYER1>
__global__ __launch_bounds__(256) void agg_k(const float* __restrict__ Z,
                                             const float* __restrict__ el,
                                             const float* __restrict__ er,
                                             const float* __restrict__ bias,
                                             const int* __restrict__ offs,
                                             const int* __restrict__ esrc,
                                             float* __restrict__ out, int N) {
  int n = blockIdx.x;
  int t = threadIdx.x;
  int h = t >> 5;
  int f = t & 31;
  int beg = offs[n], end = offs[n + 1];
  float er_h = er[(size_t)n * 8 + h];
  float m = -INFINITY, s = 0.f, acc = 0.f;
  for (int i = beg; i < end; ++i) {
    int sidx = esrc[i];
    float e = el[(size_t)sidx * 8 + h] + er_h;
    e = (e >= 0.f) ? e : 0.2f * e;
    float mn = fmaxf(m, e);
    float scale = __expf(m - mn);   // first iter: exp(-inf)=0
    float p = __expf(e - mn);
    float zv = Z[(size_t)sidx * 256 + h * 32 + f];
    s = s * scale + p;
    acc = acc * scale + p * zv;
    m = mn;
  }
  __shared__ float lds[8][33];
  float v = (end > beg) ? (acc / s) : 0.f;
  v += bias[h * 32 + f];
  lds[h][f] = v;
  __syncthreads();
  if (t < 32) {
    float sum = 0.f;
#pragma unroll
    for (int hh = 0; hh < 8; ++hh) sum += lds[hh][t];
    sum *= 0.125f;
    if (LAYER1) sum = (sum > 0.f) ? sum : expm1f(sum);
    out[(size_t)n * 32 + t] = sum;
  }
}

// ---------------- launch ----------------

extern "C" void kernel_launch(void* const* d_in, const int* in_sizes, int n_in,
                              void* d_out, int out_size, void* d_ws, size_t ws_size,
                              hipStream_t stream) {
  const float* x   = (const float*)d_in[0];
  const float* W1  = (const float*)d_in[1];
  const float* al1 = (const float*)d_in[2];
  const float* ar1 = (const float*)d_in[3];
  const float* b1  = (const float*)d_in[4];
  const float* W2  = (const float*)d_in[5];
  const float* al2 = (const float*)d_in[6];
  const float* ar2 = (const float*)d_in[7];
  const float* b2  = (const float*)d_in[8];
  const int* src   = (const int*)d_in[9];
  const int* dst   = (const int*)d_in[10];
  float* out = (float*)d_out;

  const int N = in_sizes[0] / IN_F;
  const int E = in_sizes[9];

  char* p = (char*)d_ws;
  auto alloc = [&](size_t bytes) {
    char* q = p;
    p += (bytes + 255) & ~(size_t)255;
    return q;
  };
  float* z    = (float*)alloc((size_t)N * 256 * 4);  // z1, later reused as z2
  float* el   = (float*)alloc((size_t)N * 8 * 4);
  float* er   = (float*)alloc((size_t)N * 8 * 4);
  float* h1   = (float*)alloc((size_t)N * 32 * 4);
  int* offs   = (int*)alloc((size_t)(N + 1) * 4);
  int* deg    = (int*)alloc((size_t)N * 4);
  int* cursor = (int*)alloc((size_t)N * 4);
  int* bsum   = (int*)alloc((size_t)SCAN_B * 4);
  int* esrc   = (int*)alloc((size_t)E * 4);

  hipMemsetAsync(deg, 0, (size_t)N * 4, stream);
  hipMemsetAsync(cursor, 0, (size_t)N * 4, stream);

  int nb = (N + SCAN_B - 1) / SCAN_B;
  hist_k<<<(E + 255) / 256, 256, 0, stream>>>(dst, deg, E);
  scan1_k<<<nb, SCAN_B, 0, stream>>>(deg, offs, bsum, N);
  scan2_k<<<1, SCAN_B, 0, stream>>>(bsum, nb);
  scan3_k<<<nb, SCAN_B, 0, stream>>>(offs, bsum, N);
  scatter_k<<<(E + 255) / 256, 256, 0, stream>>>(src, dst, offs, cursor, esrc, E);

  // ---- layer 1 ----
  dim3 g1((N + 63) / 64, 4);
  gemm_xw_k<<<g1, 256, 0, stream>>>(x, W1, z, N, 256, 256);
  logits_k<<<(N + 3) / 4, 256, 0, stream>>>(z, al1, ar1, el, er, N);
  agg_k<true><<<N, 256, 0, stream>>>(z, el, er, b1, offs, esrc, h1, N);

  // ---- layer 2 ----
  gemm_h_k<<<(N + 15) / 16, 256, 0, stream>>>(h1, W2, z, N);
  logits_k<<<(N + 3) / 4, 256, 0, stream>>>(z, al2, ar2, el, er, N);
  agg_k<false><<<N, 256, 0, stream>>>(z, el, er, b2, offs, esrc, out, N);
}

// Round 3
// 617.810 us; speedup vs baseline: 1.1705x; 1.1705x over previous
//
#include <hip/hip_runtime.h>
#include <math.h>

#define IN_F 256
#define NHEAD 8
#define FDIM 32
#define SCAN_B 512

// ---------------- CSR build ----------------

__global__ __launch_bounds__(256) void hist_k(const int* __restrict__ dst,
                                              int* __restrict__ deg, int E) {
  int i = blockIdx.x * 256 + threadIdx.x;
  if (i < E) atomicAdd(&deg[dst[i]], 1);
}

__global__ __launch_bounds__(SCAN_B) void scan1_k(const int* __restrict__ deg,
                                                  int* __restrict__ offs,
                                                  int* __restrict__ bsum, int N) {
  __shared__ int s[SCAN_B];
  int t = threadIdx.x;
  int i = blockIdx.x * SCAN_B + t;
  s[t] = (i < N) ? deg[i] : 0;
  __syncthreads();
  for (int off = 1; off < SCAN_B; off <<= 1) {
    int add = (t >= off) ? s[t - off] : 0;
    __syncthreads();
    s[t] += add;
    __syncthreads();
  }
  if (i < N) offs[i + 1] = s[t];
  if (t == SCAN_B - 1) bsum[blockIdx.x] = s[t];
}

__global__ __launch_bounds__(SCAN_B) void scan2_k(int* __restrict__ bsum, int nb) {
  __shared__ int s[SCAN_B];
  int t = threadIdx.x;
  s[t] = (t < nb) ? bsum[t] : 0;
  __syncthreads();
  for (int off = 1; off < SCAN_B; off <<= 1) {
    int add = (t >= off) ? s[t - off] : 0;
    __syncthreads();
    s[t] += add;
    __syncthreads();
  }
  if (t < nb) bsum[t] = (t == 0) ? 0 : s[t - 1];
}

__global__ __launch_bounds__(SCAN_B) void scan3_k(int* __restrict__ offs,
                                                  const int* __restrict__ bsum, int N) {
  int i = blockIdx.x * SCAN_B + threadIdx.x;
  if (i < N) offs[i + 1] += bsum[blockIdx.x];
  if (i == 0) offs[0] = 0;
}

__global__ __launch_bounds__(256) void scatter_k(const int* __restrict__ src,
                                                 const int* __restrict__ dst,
                                                 const int* __restrict__ offs,
                                                 int* __restrict__ cursor,
                                                 int* __restrict__ esrc, int E) {
  int i = blockIdx.x * 256 + threadIdx.x;
  if (i < E) {
    int d = dst[i];
    int pos = offs[d] + atomicAdd(&cursor[d], 1);
    esrc[pos] = src[i];
  }
}

// ---------------- GEMM1: C(MxN) = A(MxK) @ B(KxN) ----------------
__global__ __launch_bounds__(256) void gemm_xw_k(const float* __restrict__ A,
                                                 const float* __restrict__ B,
                                                 float* __restrict__ C,
                                                 int M, int K, int N) {
  __shared__ float As[16][68];
  __shared__ float Bs[16][64];
  int t = threadIdx.x;
  int tx = t & 15, ty = t >> 4;
  int row0 = blockIdx.x * 64, col0 = blockIdx.y * 64;
  int lr = t >> 2, lq = t & 3;
  int br = t >> 4, bq = t & 15;
  float acc[4][4] = {};
  for (int kt = 0; kt < K; kt += 16) {
    float4 va = make_float4(0.f, 0.f, 0.f, 0.f);
    if (row0 + lr < M)
      va = *reinterpret_cast<const float4*>(&A[(size_t)(row0 + lr) * K + kt + lq * 4]);
    float4 vb = *reinterpret_cast<const float4*>(&B[(size_t)(kt + br) * N + col0 + bq * 4]);
    As[lq * 4 + 0][lr] = va.x;
    As[lq * 4 + 1][lr] = va.y;
    As[lq * 4 + 2][lr] = va.z;
    As[lq * 4 + 3][lr] = va.w;
    Bs[br][bq * 4 + 0] = vb.x;
    Bs[br][bq * 4 + 1] = vb.y;
    Bs[br][bq * 4 + 2] = vb.z;
    Bs[br][bq * 4 + 3] = vb.w;
    __syncthreads();
#pragma unroll
    for (int kk = 0; kk < 16; ++kk) {
      float4 a4 = *reinterpret_cast<const float4*>(&As[kk][ty * 4]);
      float4 b4 = *reinterpret_cast<const float4*>(&Bs[kk][tx * 4]);
      float a[4] = {a4.x, a4.y, a4.z, a4.w};
      float b[4] = {b4.x, b4.y, b4.z, b4.w};
#pragma unroll
      for (int i = 0; i < 4; ++i)
#pragma unroll
        for (int j = 0; j < 4; ++j) acc[i][j] = fmaf(a[i], b[j], acc[i][j]);
    }
    __syncthreads();
  }
#pragma unroll
  for (int i = 0; i < 4; ++i) {
    int r = row0 + ty * 4 + i;
    if (r < M)
      *reinterpret_cast<float4*>(&C[(size_t)r * N + col0 + tx * 4]) =
          make_float4(acc[i][0], acc[i][1], acc[i][2], acc[i][3]);
  }
}

// ---------------- GEMM2: Z2(Mx256) = H(Mx32) @ W2(32x256) ----------------
__global__ __launch_bounds__(256) void gemm_h_k(const float* __restrict__ Hmat,
                                                const float* __restrict__ W2,
                                                float* __restrict__ Z2, int M) {
  __shared__ float Ws[32][256];
  __shared__ float Hs[32][20];
  int t = threadIdx.x;
  for (int i = t; i < 32 * 256; i += 256) Ws[i >> 8][i & 255] = W2[i];
  int row0 = blockIdx.x * 16;
  for (int i = t; i < 16 * 32; i += 256) {
    int r = i >> 5, k = i & 31;
    Hs[k][r] = (row0 + r < M) ? Hmat[(size_t)(row0 + r) * 32 + k] : 0.f;
  }
  __syncthreads();
  int tx = t & 63, ty = t >> 6;
  float acc[4][4] = {};
#pragma unroll
  for (int k = 0; k < 32; ++k) {
    float4 a4 = *reinterpret_cast<const float4*>(&Hs[k][ty * 4]);
    float4 b4 = *reinterpret_cast<const float4*>(&Ws[k][tx * 4]);
    float a[4] = {a4.x, a4.y, a4.z, a4.w};
    float b[4] = {b4.x, b4.y, b4.z, b4.w};
#pragma unroll
    for (int i = 0; i < 4; ++i)
#pragma unroll
      for (int j = 0; j < 4; ++j) acc[i][j] = fmaf(a[i], b[j], acc[i][j]);
  }
#pragma unroll
  for (int i = 0; i < 4; ++i) {
    int r = row0 + ty * 4 + i;
    if (r < M)
      *reinterpret_cast<float4*>(&Z2[(size_t)r * 256 + tx * 4]) =
          make_float4(acc[i][0], acc[i][1], acc[i][2], acc[i][3]);
  }
}

// ---------------- attention logits ----------------
__global__ __launch_bounds__(256) void logits_k(const float* __restrict__ Z,
                                                const float* __restrict__ al,
                                                const float* __restrict__ ar,
                                                float* __restrict__ el,
                                                float* __restrict__ er, int N) {
  int wave = threadIdx.x >> 6;
  int lane = threadIdx.x & 63;
  int n = blockIdx.x * 4 + wave;
  if (n >= N) return;
  float4 z4 = reinterpret_cast<const float4*>(Z)[(size_t)n * 64 + lane];
  float4 a4 = reinterpret_cast<const float4*>(al)[lane];
  float4 r4 = reinterpret_cast<const float4*>(ar)[lane];
  float pl = z4.x * a4.x + z4.y * a4.y + z4.z * a4.z + z4.w * a4.w;
  float pr = z4.x * r4.x + z4.y * r4.y + z4.z * r4.z + z4.w * r4.w;
  pl += __shfl_xor(pl, 1); pl += __shfl_xor(pl, 2); pl += __shfl_xor(pl, 4);
  pr += __shfl_xor(pr, 1); pr += __shfl_xor(pr, 2); pr += __shfl_xor(pr, 4);
  if ((lane & 7) == 0) {
    int h = lane >> 3;
    el[(size_t)n * 8 + h] = pl;
    er[(size_t)n * 8 + h] = pr;
  }
}

// ---------------- per-(dst,head) softmax: unnormalized alpha + 1/denom ----------------
// thread g = n*8+h; 8 consecutive threads share n -> esrc broadcast, el/alf 32B coalesced.
__global__ __launch_bounds__(256) void alpha_k(const float* __restrict__ el,
                                               const float* __restrict__ er,
                                               const int* __restrict__ offs,
                                               const int* __restrict__ esrc,
                                               float* __restrict__ alf,
                                               float* __restrict__ rden, int N) {
  int g = blockIdx.x * 256 + threadIdx.x;
  if (g >= N * NHEAD) return;
  int n = g >> 3, h = g & 7;
  int beg = offs[n], end = offs[n + 1];
  float er_h = er[g];
  float m = -INFINITY;
  for (int i = beg; i < end; ++i) {
    float e = el[(size_t)esrc[i] * 8 + h] + er_h;
    e = (e >= 0.f) ? e : 0.2f * e;
    m = fmaxf(m, e);
  }
  float s = 0.f;
  for (int i = beg; i < end; ++i) {
    float e = el[(size_t)esrc[i] * 8 + h] + er_h;
    e = (e >= 0.f) ? e : 0.2f * e;
    float ex = __expf(e - m);
    alf[(size_t)i * 8 + h] = ex;
    s += ex;
  }
  rden[g] = (end > beg) ? 1.f / s : 0.f;
}

// ---------------- per-dst aggregation: one WAVE per dst node ----------------
// lane = h*8+q: head h, feature quad q (float4). Whole 1KB z-row in one
// wave-level coalesced load. No exp/rescale in the loop; normalize once at end.
template <bool LAYER1>
__global__ __launch_bounds__(256) void agg_k(const float* __restrict__ Z,
                                             const float* __restrict__ alf,
                                             const float* __restrict__ rden,
                                             const float* __restrict__ bias,
                                             const int* __restrict__ offs,
                                             const int* __restrict__ esrc,
                                             float* __restrict__ out, int N) {
  int wid = threadIdx.x >> 6, lane = threadIdx.x & 63;
  int n = blockIdx.x * 4 + wid;
  if (n >= N) return;
  int h = lane >> 3, q = lane & 7;
  int beg = offs[n], end = offs[n + 1];
  float4 acc = make_float4(0.f, 0.f, 0.f, 0.f);
#pragma unroll 4
  for (int i = beg; i < end; ++i) {
    int sidx = esrc[i];
    float a = alf[(size_t)i * 8 + h];
    float4 z4 = *reinterpret_cast<const float4*>(&Z[(size_t)sidx * 256 + h * 32 + q * 4]);
    acc.x = fmaf(a, z4.x, acc.x);
    acc.y = fmaf(a, z4.y, acc.y);
    acc.z = fmaf(a, z4.z, acc.z);
    acc.w = fmaf(a, z4.w, acc.w);
  }
  float r = rden[(size_t)n * 8 + h];
  float4 b4 = *reinterpret_cast<const float4*>(&bias[h * 32 + q * 4]);
  float4 v;
  v.x = fmaf(acc.x, r, b4.x);
  v.y = fmaf(acc.y, r, b4.y);
  v.z = fmaf(acc.z, r, b4.z);
  v.w = fmaf(acc.w, r, b4.w);
#pragma unroll
  for (int off = 8; off < 64; off <<= 1) {
    v.x += __shfl_xor(v.x, off);
    v.y += __shfl_xor(v.y, off);
    v.z += __shfl_xor(v.z, off);
    v.w += __shfl_xor(v.w, off);
  }
  if (h == 0) {
    v.x *= 0.125f; v.y *= 0.125f; v.z *= 0.125f; v.w *= 0.125f;
    if (LAYER1) {
      v.x = (v.x > 0.f) ? v.x : expm1f(v.x);
      v.y = (v.y > 0.f) ? v.y : expm1f(v.y);
      v.z = (v.z > 0.f) ? v.z : expm1f(v.z);
      v.w = (v.w > 0.f) ? v.w : expm1f(v.w);
    }
    *reinterpret_cast<float4*>(&out[(size_t)n * 32 + q * 4]) = v;
  }
}

// ---------------- launch ----------------

extern "C" void kernel_launch(void* const* d_in, const int* in_sizes, int n_in,
                              void* d_out, int out_size, void* d_ws, size_t ws_size,
                              hipStream_t stream) {
  const float* x   = (const float*)d_in[0];
  const float* W1  = (const float*)d_in[1];
  const float* al1 = (const float*)d_in[2];
  const float* ar1 = (const float*)d_in[3];
  const float* b1  = (const float*)d_in[4];
  const float* W2  = (const float*)d_in[5];
  const float* al2 = (const float*)d_in[6];
  const float* ar2 = (const float*)d_in[7];
  const float* b2  = (const float*)d_in[8];
  const int* src   = (const int*)d_in[9];
  const int* dst   = (const int*)d_in[10];
  float* out = (float*)d_out;

  const int N = in_sizes[0] / IN_F;
  const int E = in_sizes[9];

  char* p = (char*)d_ws;
  auto alloc = [&](size_t bytes) {
    char* q = p;
    p += (bytes + 255) & ~(size_t)255;
    return q;
  };
  float* z    = (float*)alloc((size_t)N * 256 * 4);  // z1, reused as z2
  float* el   = (float*)alloc((size_t)N * 8 * 4);
  float* er   = (float*)alloc((size_t)N * 8 * 4);
  float* h1   = (float*)alloc((size_t)N * 32 * 4);
  float* alf  = (float*)alloc((size_t)E * 8 * 4);    // unnormalized alpha, reused
  float* rden = (float*)alloc((size_t)N * 8 * 4);
  int* offs   = (int*)alloc((size_t)(N + 1) * 4);
  int* deg    = (int*)alloc((size_t)N * 4);
  int* cursor = (int*)alloc((size_t)N * 4);
  int* bsum   = (int*)alloc((size_t)SCAN_B * 4);
  int* esrc   = (int*)alloc((size_t)E * 4);

  hipMemsetAsync(deg, 0, (size_t)N * 4, stream);
  hipMemsetAsync(cursor, 0, (size_t)N * 4, stream);

  int nb = (N + SCAN_B - 1) / SCAN_B;
  hist_k<<<(E + 255) / 256, 256, 0, stream>>>(dst, deg, E);
  scan1_k<<<nb, SCAN_B, 0, stream>>>(deg, offs, bsum, N);
  scan2_k<<<1, SCAN_B, 0, stream>>>(bsum, nb);
  scan3_k<<<nb, SCAN_B, 0, stream>>>(offs, bsum, N);
  scatter_k<<<(E + 255) / 256, 256, 0, stream>>>(src, dst, offs, cursor, esrc, E);

  int nh_blocks = (N * NHEAD + 255) / 256;

  // ---- layer 1 ----
  dim3 g1((N + 63) / 64, 4);
  gemm_xw_k<<<g1, 256, 0, stream>>>(x, W1, z, N, 256, 256);
  logits_k<<<(N + 3) / 4, 256, 0, stream>>>(z, al1, ar1, el, er, N);
  alpha_k<<<nh_blocks, 256, 0, stream>>>(el, er, offs, esrc, alf, rden, N);
  agg_k<true><<<(N + 3) / 4, 256, 0, stream>>>(z, alf, rden, b1, offs, esrc, h1, N);

  // ---- layer 2 ----
  gemm_h_k<<<(N + 15) / 16, 256, 0, stream>>>(h1, W2, z, N);
  logits_k<<<(N + 3) / 4, 256, 0, stream>>>(z, al2, ar2, el, er, N);
  alpha_k<<<nh_blocks, 256, 0, stream>>>(el, er, offs, esrc, alf, rden, N);
  agg_k<false><<<(N + 3) / 4, 256, 0, stream>>>(z, alf, rden, b2, offs, esrc, out, N);
}

// Round 6
// 513.543 us; speedup vs baseline: 1.4081x; 1.2030x over previous
//
#include <hip/hip_runtime.h>
#include <hip/hip_fp16.h>
#include <math.h>

#define IN_F 256
#define NHEAD 8
#define FDIM 32
#define SCAN_B 512

__device__ inline unsigned pkh2(float x, float y) {
  __half2 h = __floats2half2_rn(x, y);
  return *reinterpret_cast<unsigned*>(&h);
}

// ---------------- CSR build ----------------

__global__ __launch_bounds__(256) void hist_k(const int* __restrict__ dst,
                                              int* __restrict__ deg, int E) {
  int i = blockIdx.x * 256 + threadIdx.x;
  if (i < E) atomicAdd(&deg[dst[i]], 1);
}

__global__ __launch_bounds__(SCAN_B) void scan1_k(const int* __restrict__ deg,
                                                  int* __restrict__ offs,
                                                  int* __restrict__ bsum, int N) {
  __shared__ int s[SCAN_B];
  int t = threadIdx.x;
  int i = blockIdx.x * SCAN_B + t;
  s[t] = (i < N) ? deg[i] : 0;
  __syncthreads();
  for (int off = 1; off < SCAN_B; off <<= 1) {
    int add = (t >= off) ? s[t - off] : 0;
    __syncthreads();
    s[t] += add;
    __syncthreads();
  }
  if (i < N) offs[i + 1] = s[t];
  if (t == SCAN_B - 1) bsum[blockIdx.x] = s[t];
}

__global__ __launch_bounds__(SCAN_B) void scan2_k(int* __restrict__ bsum, int nb) {
  __shared__ int s[SCAN_B];
  int t = threadIdx.x;
  s[t] = (t < nb) ? bsum[t] : 0;
  __syncthreads();
  for (int off = 1; off < SCAN_B; off <<= 1) {
    int add = (t >= off) ? s[t - off] : 0;
    __syncthreads();
    s[t] += add;
    __syncthreads();
  }
  if (t < nb) bsum[t] = (t == 0) ? 0 : s[t - 1];
}

__global__ __launch_bounds__(SCAN_B) void scan3_k(int* __restrict__ offs,
                                                  const int* __restrict__ bsum, int N) {
  int i = blockIdx.x * SCAN_B + threadIdx.x;
  if (i < N) offs[i + 1] += bsum[blockIdx.x];
  if (i == 0) offs[0] = 0;
}

__global__ __launch_bounds__(256) void scatter_k(const int* __restrict__ src,
                                                 const int* __restrict__ dst,
                                                 const int* __restrict__ offs,
                                                 int* __restrict__ cursor,
                                                 int* __restrict__ esrc, int E) {
  int i = blockIdx.x * 256 + threadIdx.x;
  if (i < E) {
    int d = dst[i];
    int pos = offs[d] + atomicAdd(&cursor[d], 1);
    esrc[pos] = src[i];
  }
}

// ---------------- GEMM1: Zh(Mx256,fp16) = A(Mx256) @ B(256x256) ----------------
// 128x128 tile, 256 threads (16x16), 8x8 per thread, K-tile 16.
// LDS sublayout: element (k,r) at [k*196 + (r>>3)*12 + (r&7)] -> b128 reads are
// 2-way bank aliased (free) instead of 4-way; bases stay 16B-aligned.
__global__ __launch_bounds__(256) void gemm_xw_k(const float* __restrict__ A,
                                                 const float* __restrict__ B,
                                                 __half* __restrict__ Zh, int M) {
  __shared__ float AsF[16 * 196];
  __shared__ float BsF[16 * 196];
  int t = threadIdx.x;
  int tx = t & 15, ty = t >> 4;
  int row0 = blockIdx.x * 128, col0 = blockIdx.y * 128;
  float acc[8][8] = {};
  for (int kt = 0; kt < 256; kt += 16) {
#pragma unroll
    for (int i = 0; i < 2; ++i) {
      int idx = t + i * 256;
      int row = idx >> 2, q = idx & 3;
      float4 va = make_float4(0.f, 0.f, 0.f, 0.f);
      if (row0 + row < M)
        va = *reinterpret_cast<const float4*>(&A[(size_t)(row0 + row) * 256 + kt + q * 4]);
      int abase = (row >> 3) * 12 + (row & 7);
      AsF[(q * 4 + 0) * 196 + abase] = va.x;
      AsF[(q * 4 + 1) * 196 + abase] = va.y;
      AsF[(q * 4 + 2) * 196 + abase] = va.z;
      AsF[(q * 4 + 3) * 196 + abase] = va.w;
      int brow = idx >> 5, bc = idx & 31;
      float4 vb = *reinterpret_cast<const float4*>(&B[(size_t)(kt + brow) * 256 + col0 + bc * 4]);
      *reinterpret_cast<float4*>(&BsF[brow * 196 + (bc >> 1) * 12 + (bc & 1) * 4]) = vb;
    }
    __syncthreads();
#pragma unroll
    for (int kk = 0; kk < 16; ++kk) {
      float a[8], b[8];
      *reinterpret_cast<float4*>(&a[0]) = *reinterpret_cast<const float4*>(&AsF[kk * 196 + ty * 12]);
      *reinterpret_cast<float4*>(&a[4]) = *reinterpret_cast<const float4*>(&AsF[kk * 196 + ty * 12 + 4]);
      *reinterpret_cast<float4*>(&b[0]) = *reinterpret_cast<const float4*>(&BsF[kk * 196 + tx * 12]);
      *reinterpret_cast<float4*>(&b[4]) = *reinterpret_cast<const float4*>(&BsF[kk * 196 + tx * 12 + 4]);
#pragma unroll
      for (int i = 0; i < 8; ++i)
#pragma unroll
        for (int j = 0; j < 8; ++j) acc[i][j] = fmaf(a[i], b[j], acc[i][j]);
    }
    __syncthreads();
  }
#pragma unroll
  for (int i = 0; i < 8; ++i) {
    int r = row0 + ty * 8 + i;
    if (r < M) {
      uint4 w;
      w.x = pkh2(acc[i][0], acc[i][1]);
      w.y = pkh2(acc[i][2], acc[i][3]);
      w.z = pkh2(acc[i][4], acc[i][5]);
      w.w = pkh2(acc[i][6], acc[i][7]);
      *reinterpret_cast<uint4*>(&Zh[(size_t)r * 256 + col0 + tx * 8]) = w;
    }
  }
}

// ---------------- GEMM2: Zh(Mx256,fp16) = H(Mx32) @ W2(32x256) ----------------
__global__ __launch_bounds__(256) void gemm_h_k(const float* __restrict__ Hmat,
                                                const float* __restrict__ W2,
                                                __half* __restrict__ Zh, int M) {
  __shared__ float Ws[32][256];
  __shared__ float Hs[32][20];
  int t = threadIdx.x;
  for (int i = t; i < 32 * 256; i += 256) Ws[i >> 8][i & 255] = W2[i];
  int row0 = blockIdx.x * 16;
  for (int i = t; i < 16 * 32; i += 256) {
    int r = i >> 5, k = i & 31;
    Hs[k][r] = (row0 + r < M) ? Hmat[(size_t)(row0 + r) * 32 + k] : 0.f;
  }
  __syncthreads();
  int tx = t & 63, ty = t >> 6;
  float acc[4][4] = {};
#pragma unroll
  for (int k = 0; k < 32; ++k) {
    float4 a4 = *reinterpret_cast<const float4*>(&Hs[k][ty * 4]);
    float4 b4 = *reinterpret_cast<const float4*>(&Ws[k][tx * 4]);
    float a[4] = {a4.x, a4.y, a4.z, a4.w};
    float b[4] = {b4.x, b4.y, b4.z, b4.w};
#pragma unroll
    for (int i = 0; i < 4; ++i)
#pragma unroll
      for (int j = 0; j < 4; ++j) acc[i][j] = fmaf(a[i], b[j], acc[i][j]);
  }
#pragma unroll
  for (int i = 0; i < 4; ++i) {
    int r = row0 + ty * 4 + i;
    if (r < M) {
      uint2 w;
      w.x = pkh2(acc[i][0], acc[i][1]);
      w.y = pkh2(acc[i][2], acc[i][3]);
      *reinterpret_cast<uint2*>(&Zh[(size_t)r * 256 + tx * 4]) = w;
    }
  }
}

// ---------------- attention logits (fp16 z) ----------------
__global__ __launch_bounds__(256) void logits_k(const __half* __restrict__ Zh,
                                                const float* __restrict__ al,
                                                const float* __restrict__ ar,
                                                float* __restrict__ el,
                                                float* __restrict__ er, int N) {
  int wave = threadIdx.x >> 6;
  int lane = threadIdx.x & 63;
  int n = blockIdx.x * 4 + wave;
  if (n >= N) return;
  uint2 u = *reinterpret_cast<const uint2*>(&Zh[(size_t)n * 256 + lane * 4]);
  float2 f0 = __half22float2(*reinterpret_cast<__half2*>(&u.x));
  float2 f1 = __half22float2(*reinterpret_cast<__half2*>(&u.y));
  float4 a4 = reinterpret_cast<const float4*>(al)[lane];
  float4 r4 = reinterpret_cast<const float4*>(ar)[lane];
  float pl = f0.x * a4.x + f0.y * a4.y + f1.x * a4.z + f1.y * a4.w;
  float pr = f0.x * r4.x + f0.y * r4.y + f1.x * r4.z + f1.y * r4.w;
  pl += __shfl_xor(pl, 1); pl += __shfl_xor(pl, 2); pl += __shfl_xor(pl, 4);
  pr += __shfl_xor(pr, 1); pr += __shfl_xor(pr, 2); pr += __shfl_xor(pr, 4);
  if ((lane & 7) == 0) {
    int h = lane >> 3;
    el[(size_t)n * 8 + h] = pl;
    er[(size_t)n * 8 + h] = pr;
  }
}

// ---------------- per-(dst,head) softmax: unnormalized alpha + 1/denom ----------------
__global__ __launch_bounds__(256) void alpha_k(const float* __restrict__ el,
                                               const float* __restrict__ er,
                                               const int* __restrict__ offs,
                                               const int* __restrict__ esrc,
                                               float* __restrict__ alf,
                                               float* __restrict__ rden, int N) {
  int g = blockIdx.x * 256 + threadIdx.x;
  if (g >= N * NHEAD) return;
  int n = g >> 3, h = g & 7;
  int beg = offs[n], end = offs[n + 1];
  float er_h = er[g];
  float m = -INFINITY;
  for (int i = beg; i < end; ++i) {
    float e = el[(size_t)esrc[i] * 8 + h] + er_h;
    e = (e >= 0.f) ? e : 0.2f * e;
    m = fmaxf(m, e);
  }
  float s = 0.f;
  for (int i = beg; i < end; ++i) {
    float e = el[(size_t)esrc[i] * 8 + h] + er_h;
    e = (e >= 0.f) ? e : 0.2f * e;
    float ex = __expf(e - m);
    alf[(size_t)i * 8 + h] = ex;
    s += ex;
  }
  rden[g] = (end > beg) ? 1.f / s : 0.f;
}

// ---------------- per-dst aggregation: one WAVE per dst, fp16 z gather ----------------
// lane = h*8+q: head h, 4 features q*4..q*4+3 (8B fp16 load per lane = 512B/row/wave).
template <bool LAYER1>
__global__ __launch_bounds__(256) void agg_k(const __half* __restrict__ Zh,
                                             const float* __restrict__ alf,
                                             const float* __restrict__ rden,
                                             const float* __restrict__ bias,
                                             const int* __restrict__ offs,
                                             const int* __restrict__ esrc,
                                             float* __restrict__ out, int N) {
  int wid = threadIdx.x >> 6, lane = threadIdx.x & 63;
  int n = blockIdx.x * 4 + wid;
  if (n >= N) return;
  int h = lane >> 3, q = lane & 7;
  int beg = offs[n], end = offs[n + 1];
  float4 acc = make_float4(0.f, 0.f, 0.f, 0.f);
#pragma unroll 4
  for (int i = beg; i < end; ++i) {
    int sidx = esrc[i];
    float a = alf[(size_t)i * 8 + h];
    uint2 u = *reinterpret_cast<const uint2*>(&Zh[(size_t)sidx * 256 + h * 32 + q * 4]);
    float2 f0 = __half22float2(*reinterpret_cast<__half2*>(&u.x));
    float2 f1 = __half22float2(*reinterpret_cast<__half2*>(&u.y));
    acc.x = fmaf(a, f0.x, acc.x);
    acc.y = fmaf(a, f0.y, acc.y);
    acc.z = fmaf(a, f1.x, acc.z);
    acc.w = fmaf(a, f1.y, acc.w);
  }
  float r = rden[(size_t)n * 8 + h];
  float4 b4 = *reinterpret_cast<const float4*>(&bias[h * 32 + q * 4]);
  float4 v;
  v.x = fmaf(acc.x, r, b4.x);
  v.y = fmaf(acc.y, r, b4.y);
  v.z = fmaf(acc.z, r, b4.z);
  v.w = fmaf(acc.w, r, b4.w);
#pragma unroll
  for (int off = 8; off < 64; off <<= 1) {
    v.x += __shfl_xor(v.x, off);
    v.y += __shfl_xor(v.y, off);
    v.z += __shfl_xor(v.z, off);
    v.w += __shfl_xor(v.w, off);
  }
  if (h == 0) {
    v.x *= 0.125f; v.y *= 0.125f; v.z *= 0.125f; v.w *= 0.125f;
    if (LAYER1) {
      v.x = (v.x > 0.f) ? v.x : expm1f(v.x);
      v.y = (v.y > 0.f) ? v.y : expm1f(v.y);
      v.z = (v.z > 0.f) ? v.z : expm1f(v.z);
      v.w = (v.w > 0.f) ? v.w : expm1f(v.w);
    }
    *reinterpret_cast<float4*>(&out[(size_t)n * 32 + q * 4]) = v;
  }
}

// ---------------- launch ----------------

extern "C" void kernel_launch(void* const* d_in, const int* in_sizes, int n_in,
                              void* d_out, int out_size, void* d_ws, size_t ws_size,
                              hipStream_t stream) {
  const float* x   = (const float*)d_in[0];
  const float* W1  = (const float*)d_in[1];
  const float* al1 = (const float*)d_in[2];
  const float* ar1 = (const float*)d_in[3];
  const float* b1  = (const float*)d_in[4];
  const float* W2  = (const float*)d_in[5];
  const float* al2 = (const float*)d_in[6];
  const float* ar2 = (const float*)d_in[7];
  const float* b2  = (const float*)d_in[8];
  const int* src   = (const int*)d_in[9];
  const int* dst   = (const int*)d_in[10];
  float* out = (float*)d_out;

  const int N = in_sizes[0] / IN_F;
  const int E = in_sizes[9];

  char* p = (char*)d_ws;
  auto alloc = [&](size_t bytes) {
    char* q = p;
    p += (bytes + 255) & ~(size_t)255;
    return q;
  };
  __half* zh  = (__half*)alloc((size_t)N * 256 * 2);  // z1 fp16, reused as z2
  float* el   = (float*)alloc((size_t)N * 8 * 4);
  float* er   = (float*)alloc((size_t)N * 8 * 4);
  float* h1   = (float*)alloc((size_t)N * 32 * 4);
  float* alf  = (float*)alloc((size_t)E * 8 * 4);
  float* rden = (float*)alloc((size_t)N * 8 * 4);
  int* offs   = (int*)alloc((size_t)(N + 1) * 4);
  int* deg    = (int*)alloc((size_t)N * 4);
  int* cursor = (int*)alloc((size_t)N * 4);
  int* bsum   = (int*)alloc((size_t)SCAN_B * 4);
  int* esrc   = (int*)alloc((size_t)E * 4);

  hipMemsetAsync(deg, 0, (size_t)N * 4, stream);
  hipMemsetAsync(cursor, 0, (size_t)N * 4, stream);

  int nb = (N + SCAN_B - 1) / SCAN_B;
  hist_k<<<(E + 255) / 256, 256, 0, stream>>>(dst, deg, E);
  scan1_k<<<nb, SCAN_B, 0, stream>>>(deg, offs, bsum, N);
  scan2_k<<<1, SCAN_B, 0, stream>>>(bsum, nb);
  scan3_k<<<nb, SCAN_B, 0, stream>>>(offs, bsum, N);
  scatter_k<<<(E + 255) / 256, 256, 0, stream>>>(src, dst, offs, cursor, esrc, E);

  int nh_blocks = (N * NHEAD + 255) / 256;

  // ---- layer 1 ----
  dim3 g1((N + 127) / 128, 2);
  gemm_xw_k<<<g1, 256, 0, stream>>>(x, W1, zh, N);
  logits_k<<<(N + 3) / 4, 256, 0, stream>>>(zh, al1, ar1, el, er, N);
  alpha_k<<<nh_blocks, 256, 0, stream>>>(el, er, offs, esrc, alf, rden, N);
  agg_k<true><<<(N + 3) / 4, 256, 0, stream>>>(zh, alf, rden, b1, offs, esrc, h1, N);

  // ---- layer 2 ----
  gemm_h_k<<<(N + 15) / 16, 256, 0, stream>>>(h1, W2, zh, N);
  logits_k<<<(N + 3) / 4, 256, 0, stream>>>(zh, al2, ar2, el, er, N);
  alpha_k<<<nh_blocks, 256, 0, stream>>>(el, er, offs, esrc, alf, rden, N);
  agg_k<false><<<(N + 3) / 4, 256, 0, stream>>>(zh, alf, rden, b2, offs, esrc, out, N);
}

// Round 7
// 482.961 us; speedup vs baseline: 1.4973x; 1.0633x over previous
//
#include <hip/hip_runtime.h>
#include <hip/hip_fp16.h>
#include <math.h>

#define IN_F 256
#define NHEAD 8
#define FDIM 32
#define SCAN_B 512

typedef _Float16 f16x8 __attribute__((ext_vector_type(8)));
typedef float f32x4 __attribute__((ext_vector_type(4)));

__device__ inline unsigned pkh2(float x, float y) {
  __half2 h = __floats2half2_rn(x, y);
  return *reinterpret_cast<unsigned*>(&h);
}

// ---------------- CSR build ----------------

__global__ __launch_bounds__(256) void hist_k(const int* __restrict__ dst,
                                              int* __restrict__ deg, int E) {
  int i = blockIdx.x * 256 + threadIdx.x;
  if (i < E) atomicAdd(&deg[dst[i]], 1);
}

__global__ __launch_bounds__(SCAN_B) void scan1_k(const int* __restrict__ deg,
                                                  int* __restrict__ offs,
                                                  int* __restrict__ bsum, int N) {
  __shared__ int s[SCAN_B];
  int t = threadIdx.x;
  int i = blockIdx.x * SCAN_B + t;
  s[t] = (i < N) ? deg[i] : 0;
  __syncthreads();
  for (int off = 1; off < SCAN_B; off <<= 1) {
    int add = (t >= off) ? s[t - off] : 0;
    __syncthreads();
    s[t] += add;
    __syncthreads();
  }
  if (i < N) offs[i + 1] = s[t];
  if (t == SCAN_B - 1) bsum[blockIdx.x] = s[t];
}

__global__ __launch_bounds__(SCAN_B) void scan2_k(int* __restrict__ bsum, int nb) {
  __shared__ int s[SCAN_B];
  int t = threadIdx.x;
  s[t] = (t < nb) ? bsum[t] : 0;
  __syncthreads();
  for (int off = 1; off < SCAN_B; off <<= 1) {
    int add = (t >= off) ? s[t - off] : 0;
    __syncthreads();
    s[t] += add;
    __syncthreads();
  }
  if (t < nb) bsum[t] = (t == 0) ? 0 : s[t - 1];
}

__global__ __launch_bounds__(SCAN_B) void scan3_k(int* __restrict__ offs,
                                                  const int* __restrict__ bsum, int N) {
  int i = blockIdx.x * SCAN_B + threadIdx.x;
  if (i < N) offs[i + 1] += bsum[blockIdx.x];
  if (i == 0) offs[0] = 0;
}

__global__ __launch_bounds__(256) void scatter_k(const int* __restrict__ src,
                                                 const int* __restrict__ dst,
                                                 const int* __restrict__ offs,
                                                 int* __restrict__ cursor,
                                                 int* __restrict__ esrc, int E) {
  int i = blockIdx.x * 256 + threadIdx.x;
  if (i < E) {
    int d = dst[i];
    int pos = offs[d] + atomicAdd(&cursor[d], 1);
    esrc[pos] = src[i];
  }
}

// ---------------- W1 transpose + fp16 cast: W1t[n][k] = (half)W1[k][n] ----------------
__global__ __launch_bounds__(256) void w1cvt_k(const float* __restrict__ W1,
                                               __half* __restrict__ W1t) {
  __shared__ float s[16][17];
  int bx = blockIdx.x * 16, by = blockIdx.y * 16;
  int tx = threadIdx.x, ty = threadIdx.y;
  s[ty][tx] = W1[(by + ty) * 256 + bx + tx];   // coalesced read over n
  __syncthreads();
  W1t[(size_t)(bx + ty) * 256 + by + tx] = __float2half(s[tx][ty]);  // coalesced over k
}

// ---------------- GEMM1 via MFMA: Zh(Mx256,fp16) = X(Mx256,fp32) @ W1 ----------------
// 256 threads = 4 waves, each wave owns 16 rows x all 256 cols. No LDS.
// A: x fp32 loaded 32B/lane and converted in-register (32 VGPRs hold K=256 strip).
// B: W1t[n][k] fp16, 16B contiguous frags, L2-resident (128 KB).
// mfma_f32_16x16x32_f16 layout: A[l&15][(l>>4)*8+j], B[(l>>4)*8+j][l&15],
// D row=(l>>4)*4+i, col=l&15.
__global__ __launch_bounds__(256) void gemm_xw_mfma_k(const float* __restrict__ X,
                                                      const __half* __restrict__ W1t,
                                                      __half* __restrict__ Zh, int M) {
  int t = threadIdx.x;
  int wv = t >> 6, l = t & 63;
  int r = l & 15, kg = l >> 4;
  int row0 = blockIdx.x * 64 + wv * 16;
  int row = row0 + r;
  int rowc = (row < M) ? row : (M - 1);   // clamp; OOB rows never stored

  f16x8 a[8];
  const float* xp = X + (size_t)rowc * 256 + kg * 8;
#pragma unroll
  for (int ks = 0; ks < 8; ++ks) {
    float4 f0 = *reinterpret_cast<const float4*>(xp + ks * 32);
    float4 f1 = *reinterpret_cast<const float4*>(xp + ks * 32 + 4);
    f16x8 av;
    av[0] = (_Float16)f0.x; av[1] = (_Float16)f0.y;
    av[2] = (_Float16)f0.z; av[3] = (_Float16)f0.w;
    av[4] = (_Float16)f1.x; av[5] = (_Float16)f1.y;
    av[6] = (_Float16)f1.z; av[7] = (_Float16)f1.w;
    a[ks] = av;
  }

#pragma unroll 4
  for (int nf = 0; nf < 16; ++nf) {
    int col = nf * 16 + r;
    const f16x8* bp = reinterpret_cast<const f16x8*>(W1t + (size_t)col * 256 + kg * 8);
    f32x4 acc = {0.f, 0.f, 0.f, 0.f};
#pragma unroll
    for (int ks = 0; ks < 8; ++ks) {
      f16x8 bv = bp[ks * 4];  // + ks*32 halves
      acc = __builtin_amdgcn_mfma_f32_16x16x32_f16(a[ks], bv, acc, 0, 0, 0);
    }
    int orow = row0 + kg * 4;
#pragma unroll
    for (int i = 0; i < 4; ++i) {
      if (orow + i < M)
        Zh[(size_t)(orow + i) * 256 + nf * 16 + r] = __float2half((float)acc[i]);
    }
  }
}

// ---------------- GEMM2: Zh(Mx256,fp16) = H(Mx32) @ W2(32x256) ----------------
__global__ __launch_bounds__(256) void gemm_h_k(const float* __restrict__ Hmat,
                                                const float* __restrict__ W2,
                                                __half* __restrict__ Zh, int M) {
  __shared__ float Ws[32][256];
  __shared__ float Hs[32][20];
  int t = threadIdx.x;
  for (int i = t; i < 32 * 256; i += 256) Ws[i >> 8][i & 255] = W2[i];
  int row0 = blockIdx.x * 16;
  for (int i = t; i < 16 * 32; i += 256) {
    int r = i >> 5, k = i & 31;
    Hs[k][r] = (row0 + r < M) ? Hmat[(size_t)(row0 + r) * 32 + k] : 0.f;
  }
  __syncthreads();
  int tx = t & 63, ty = t >> 6;
  float acc[4][4] = {};
#pragma unroll
  for (int k = 0; k < 32; ++k) {
    float4 a4 = *reinterpret_cast<const float4*>(&Hs[k][ty * 4]);
    float4 b4 = *reinterpret_cast<const float4*>(&Ws[k][tx * 4]);
    float a[4] = {a4.x, a4.y, a4.z, a4.w};
    float b[4] = {b4.x, b4.y, b4.z, b4.w};
#pragma unroll
    for (int i = 0; i < 4; ++i)
#pragma unroll
      for (int j = 0; j < 4; ++j) acc[i][j] = fmaf(a[i], b[j], acc[i][j]);
  }
#pragma unroll
  for (int i = 0; i < 4; ++i) {
    int r = row0 + ty * 4 + i;
    if (r < M) {
      uint2 w;
      w.x = pkh2(acc[i][0], acc[i][1]);
      w.y = pkh2(acc[i][2], acc[i][3]);
      *reinterpret_cast<uint2*>(&Zh[(size_t)r * 256 + tx * 4]) = w;
    }
  }
}

// ---------------- attention logits (fp16 z) ----------------
__global__ __launch_bounds__(256) void logits_k(const __half* __restrict__ Zh,
                                                const float* __restrict__ al,
                                                const float* __restrict__ ar,
                                                float* __restrict__ el,
                                                float* __restrict__ er, int N) {
  int wave = threadIdx.x >> 6;
  int lane = threadIdx.x & 63;
  int n = blockIdx.x * 4 + wave;
  if (n >= N) return;
  uint2 u = *reinterpret_cast<const uint2*>(&Zh[(size_t)n * 256 + lane * 4]);
  float2 f0 = __half22float2(*reinterpret_cast<__half2*>(&u.x));
  float2 f1 = __half22float2(*reinterpret_cast<__half2*>(&u.y));
  float4 a4 = reinterpret_cast<const float4*>(al)[lane];
  float4 r4 = reinterpret_cast<const float4*>(ar)[lane];
  float pl = f0.x * a4.x + f0.y * a4.y + f1.x * a4.z + f1.y * a4.w;
  float pr = f0.x * r4.x + f0.y * r4.y + f1.x * r4.z + f1.y * r4.w;
  pl += __shfl_xor(pl, 1); pl += __shfl_xor(pl, 2); pl += __shfl_xor(pl, 4);
  pr += __shfl_xor(pr, 1); pr += __shfl_xor(pr, 2); pr += __shfl_xor(pr, 4);
  if ((lane & 7) == 0) {
    int h = lane >> 3;
    el[(size_t)n * 8 + h] = pl;
    er[(size_t)n * 8 + h] = pr;
  }
}

// ---------------- per-(dst,head) softmax: unnormalized alpha + 1/denom ----------------
__global__ __launch_bounds__(256) void alpha_k(const float* __restrict__ el,
                                               const float* __restrict__ er,
                                               const int* __restrict__ offs,
                                               const int* __restrict__ esrc,
                                               float* __restrict__ alf,
                                               float* __restrict__ rden, int N) {
  int g = blockIdx.x * 256 + threadIdx.x;
  if (g >= N * NHEAD) return;
  int n = g >> 3, h = g & 7;
  int beg = offs[n], end = offs[n + 1];
  float er_h = er[g];
  float m = -INFINITY;
  for (int i = beg; i < end; ++i) {
    float e = el[(size_t)esrc[i] * 8 + h] + er_h;
    e = (e >= 0.f) ? e : 0.2f * e;
    m = fmaxf(m, e);
  }
  float s = 0.f;
  for (int i = beg; i < end; ++i) {
    float e = el[(size_t)esrc[i] * 8 + h] + er_h;
    e = (e >= 0.f) ? e : 0.2f * e;
    float ex = __expf(e - m);
    alf[(size_t)i * 8 + h] = ex;
    s += ex;
  }
  rden[g] = (end > beg) ? 1.f / s : 0.f;
}

// ---------------- per-dst aggregation: one WAVE per dst, fp16 z gather ----------------
template <bool LAYER1>
__global__ __launch_bounds__(256) void agg_k(const __half* __restrict__ Zh,
                                             const float* __restrict__ alf,
                                             const float* __restrict__ rden,
                                             const float* __restrict__ bias,
                                             const int* __restrict__ offs,
                                             const int* __restrict__ esrc,
                                             float* __restrict__ out, int N) {
  int wid = threadIdx.x >> 6, lane = threadIdx.x & 63;
  int n = blockIdx.x * 4 + wid;
  if (n >= N) return;
  int h = lane >> 3, q = lane & 7;
  int beg = offs[n], end = offs[n + 1];
  float4 acc = make_float4(0.f, 0.f, 0.f, 0.f);
#pragma unroll 4
  for (int i = beg; i < end; ++i) {
    int sidx = esrc[i];
    float a = alf[(size_t)i * 8 + h];
    uint2 u = *reinterpret_cast<const uint2*>(&Zh[(size_t)sidx * 256 + h * 32 + q * 4]);
    float2 f0 = __half22float2(*reinterpret_cast<__half2*>(&u.x));
    float2 f1 = __half22float2(*reinterpret_cast<__half2*>(&u.y));
    acc.x = fmaf(a, f0.x, acc.x);
    acc.y = fmaf(a, f0.y, acc.y);
    acc.z = fmaf(a, f1.x, acc.z);
    acc.w = fmaf(a, f1.y, acc.w);
  }
  float r = rden[(size_t)n * 8 + h];
  float4 b4 = *reinterpret_cast<const float4*>(&bias[h * 32 + q * 4]);
  float4 v;
  v.x = fmaf(acc.x, r, b4.x);
  v.y = fmaf(acc.y, r, b4.y);
  v.z = fmaf(acc.z, r, b4.z);
  v.w = fmaf(acc.w, r, b4.w);
#pragma unroll
  for (int off = 8; off < 64; off <<= 1) {
    v.x += __shfl_xor(v.x, off);
    v.y += __shfl_xor(v.y, off);
    v.z += __shfl_xor(v.z, off);
    v.w += __shfl_xor(v.w, off);
  }
  if (h == 0) {
    v.x *= 0.125f; v.y *= 0.125f; v.z *= 0.125f; v.w *= 0.125f;
    if (LAYER1) {
      v.x = (v.x > 0.f) ? v.x : expm1f(v.x);
      v.y = (v.y > 0.f) ? v.y : expm1f(v.y);
      v.z = (v.z > 0.f) ? v.z : expm1f(v.z);
      v.w = (v.w > 0.f) ? v.w : expm1f(v.w);
    }
    *reinterpret_cast<float4*>(&out[(size_t)n * 32 + q * 4]) = v;
  }
}

// ---------------- launch ----------------

extern "C" void kernel_launch(void* const* d_in, const int* in_sizes, int n_in,
                              void* d_out, int out_size, void* d_ws, size_t ws_size,
                              hipStream_t stream) {
  const float* x   = (const float*)d_in[0];
  const float* W1  = (const float*)d_in[1];
  const float* al1 = (const float*)d_in[2];
  const float* ar1 = (const float*)d_in[3];
  const float* b1  = (const float*)d_in[4];
  const float* W2  = (const float*)d_in[5];
  const float* al2 = (const float*)d_in[6];
  const float* ar2 = (const float*)d_in[7];
  const float* b2  = (const float*)d_in[8];
  const int* src   = (const int*)d_in[9];
  const int* dst   = (const int*)d_in[10];
  float* out = (float*)d_out;

  const int N = in_sizes[0] / IN_F;
  const int E = in_sizes[9];

  char* p = (char*)d_ws;
  auto alloc = [&](size_t bytes) {
    char* q = p;
    p += (bytes + 255) & ~(size_t)255;
    return q;
  };
  __half* zh  = (__half*)alloc((size_t)N * 256 * 2);  // z1 fp16, reused as z2
  __half* w1t = (__half*)alloc((size_t)256 * 256 * 2);
  float* el   = (float*)alloc((size_t)N * 8 * 4);
  float* er   = (float*)alloc((size_t)N * 8 * 4);
  float* h1   = (float*)alloc((size_t)N * 32 * 4);
  float* alf  = (float*)alloc((size_t)E * 8 * 4);
  float* rden = (float*)alloc((size_t)N * 8 * 4);
  int* offs   = (int*)alloc((size_t)(N + 1) * 4);
  int* deg    = (int*)alloc((size_t)N * 4);
  int* cursor = (int*)alloc((size_t)N * 4);
  int* bsum   = (int*)alloc((size_t)SCAN_B * 4);
  int* esrc   = (int*)alloc((size_t)E * 4);

  hipMemsetAsync(deg, 0, (size_t)N * 4, stream);
  hipMemsetAsync(cursor, 0, (size_t)N * 4, stream);

  int nb = (N + SCAN_B - 1) / SCAN_B;
  hist_k<<<(E + 255) / 256, 256, 0, stream>>>(dst, deg, E);
  scan1_k<<<nb, SCAN_B, 0, stream>>>(deg, offs, bsum, N);
  scan2_k<<<1, SCAN_B, 0, stream>>>(bsum, nb);
  scan3_k<<<nb, SCAN_B, 0, stream>>>(offs, bsum, N);
  scatter_k<<<(E + 255) / 256, 256, 0, stream>>>(src, dst, offs, cursor, esrc, E);

  int nh_blocks = (N * NHEAD + 255) / 256;

  // ---- layer 1 ----
  w1cvt_k<<<dim3(16, 16), dim3(16, 16), 0, stream>>>(W1, w1t);
  gemm_xw_mfma_k<<<(N + 63) / 64, 256, 0, stream>>>(x, w1t, zh, N);
  logits_k<<<(N + 3) / 4, 256, 0, stream>>>(zh, al1, ar1, el, er, N);
  alpha_k<<<nh_blocks, 256, 0, stream>>>(el, er, offs, esrc, alf, rden, N);
  agg_k<true><<<(N + 3) / 4, 256, 0, stream>>>(zh, alf, rden, b1, offs, esrc, h1, N);

  // ---- layer 2 ----
  gemm_h_k<<<(N + 15) / 16, 256, 0, stream>>>(h1, W2, zh, N);
  logits_k<<<(N + 3) / 4, 256, 0, stream>>>(zh, al2, ar2, el, er, N);
  alpha_k<<<nh_blocks, 256, 0, stream>>>(el, er, offs, esrc, alf, rden, N);
  agg_k<false><<<(N + 3) / 4, 256, 0, stream>>>(zh, alf, rden, b2, offs, esrc, out, N);
}